// Round 16
// baseline (405.425 us; speedup 1.0000x reference)
//
#include <hip/hip_runtime.h>
#include <hip/hip_bf16.h>

#define HID 16
#define NFEAT 512
#define BW 64           // nodes per bucket (dst >> 6)
#define CH 16384        // edges per histogram/scatter block
#define MAXB 2048       // max buckets supported by bucket path
#define SCAP 5120       // ksort LDS staging capacity (int2)

typedef __attribute__((ext_vector_type(8))) short bf16x8;
typedef __attribute__((ext_vector_type(4))) float f32x4;

__device__ __forceinline__ unsigned short f2b_hw(float f) {
    __hip_bfloat16 h = __float2bfloat16(f);
    return *reinterpret_cast<unsigned short*>(&h);
}
__device__ __forceinline__ float b2f(unsigned short b) {
    return __uint_as_float(((unsigned)b) << 16);
}

// ================= bucket build (proven round 8) =================
__global__ __launch_bounds__(1024) void khist(const int* __restrict__ dst,
                                              int* __restrict__ gcount, int e, int nbkt) {
    __shared__ int hist[MAXB];
    for (int t = threadIdx.x; t < nbkt; t += 1024) hist[t] = 0;
    __syncthreads();
    int base = blockIdx.x * CH;
#pragma unroll
    for (int k = 0; k < CH / 1024; ++k) {
        int i = base + k * 1024 + threadIdx.x;
        if (i < e) atomicAdd(&hist[dst[i] >> 6], 1);
    }
    __syncthreads();
    for (int t = threadIdx.x; t < nbkt; t += 1024)
        if (hist[t]) atomicAdd(&gcount[t], hist[t]);
}

__global__ __launch_bounds__(1024) void kscan(const int* __restrict__ gcount,
                                              int* __restrict__ goff,
                                              int* __restrict__ gcursor, int nbkt) {
    __shared__ int buf0[MAXB], buf1[MAXB];
    for (int t = threadIdx.x; t < MAXB; t += 1024) buf0[t] = (t < nbkt) ? gcount[t] : 0;
    __syncthreads();
    int* in = buf0; int* out = buf1;
    for (int d = 1; d < MAXB; d <<= 1) {
        for (int t = threadIdx.x; t < MAXB; t += 1024)
            out[t] = in[t] + (t >= d ? in[t - d] : 0);
        __syncthreads();
        int* tmp = in; in = out; out = tmp;
    }
    for (int t = threadIdx.x; t < nbkt; t += 1024) {
        int excl = in[t] - gcount[t];
        goff[t] = excl;
        gcursor[t] = excl;
    }
    if (threadIdx.x == 0) goff[nbkt] = in[nbkt - 1];
}

__global__ __launch_bounds__(1024) void kscatter(const int* __restrict__ src,
                                                 const int* __restrict__ dst,
                                                 int* __restrict__ gcursor,
                                                 int2* __restrict__ pairs, int e, int nbkt) {
    __shared__ int hist[MAXB];
    __shared__ int base[MAXB];
    for (int t = threadIdx.x; t < nbkt; t += 1024) hist[t] = 0;
    __syncthreads();
    int b0 = blockIdx.x * CH;
#pragma unroll
    for (int k = 0; k < CH / 1024; ++k) {
        int i = b0 + k * 1024 + threadIdx.x;
        if (i < e) atomicAdd(&hist[dst[i] >> 6], 1);
    }
    __syncthreads();
    for (int t = threadIdx.x; t < nbkt; t += 1024)
        base[t] = hist[t] ? atomicAdd(&gcursor[t], hist[t]) : 0;
    __syncthreads();
#pragma unroll
    for (int k = 0; k < CH / 1024; ++k) {
        int i = b0 + k * 1024 + threadIdx.x;
        if (i < e) {
            int d = dst[i];
            int pos = atomicAdd(&base[d >> 6], 1);   // LDS bump
            pairs[pos] = make_int2(src[i], d);
        }
    }
}

// ================= per-bucket counting sort by dst + dis (proven r13) =======
__global__ __launch_bounds__(256) void ksort(int2* __restrict__ pairs,
                                             const int* __restrict__ goff,
                                             float* __restrict__ dis, int n) {
    __shared__ int cnt[BW];
    __shared__ int ofs[BW];
    __shared__ int2 stg[SCAP];
    int b = blockIdx.x;
    int s0 = goff[b], s1 = goff[b + 1];
    int m = s1 - s0;
    if (threadIdx.x < BW) cnt[threadIdx.x] = 0;
    __syncthreads();
    bool fits = (m <= SCAP);
    if (fits) {
        for (int i = threadIdx.x; i < m; i += 256) {
            int2 p = pairs[s0 + i];
            stg[i] = p;
            atomicAdd(&cnt[p.y & (BW - 1)], 1);
        }
    } else {
        for (int i = threadIdx.x; i < m; i += 256)
            atomicAdd(&cnt[pairs[s0 + i].y & (BW - 1)], 1);
    }
    __syncthreads();
    if (threadIdx.x < BW) {
        int node = b * BW + threadIdx.x;
        if (node < n) dis[node] = rsqrtf(1.0f + (float)cnt[threadIdx.x]);
        int v = cnt[threadIdx.x];
        int inc = v;
        for (int d = 1; d < 64; d <<= 1) {
            int o = __shfl_up(inc, d);
            if (threadIdx.x >= (unsigned)d) inc += o;
        }
        ofs[threadIdx.x] = inc - v;
    }
    __syncthreads();
    if (fits) {
        for (int i = threadIdx.x; i < m; i += 256) {
            int2 p = stg[i];
            int pos = atomicAdd(&ofs[p.y & (BW - 1)], 1);
            pairs[s0 + pos] = p;
        }
    }
}

// ================= W1 -> Wt (bf16 transposed) =================
__global__ __launch_bounds__(256) void prep_wt(const float* __restrict__ W1,
                                               unsigned short* __restrict__ Wt) {
    int i = blockIdx.x * 256 + threadIdx.x;   // 8192 = 16*512
    int j = i >> 9, k = i & 511;
    Wt[i] = f2b_hw(W1[k * HID + j]);
}

// ================= h1 = x @ W1 via MFMA (proven round 7) =================
__global__ __launch_bounds__(256) void mm1_mfma(const float* __restrict__ x,
                                                const unsigned short* __restrict__ Wt,
                                                const float* __restrict__ dis,
                                                float* __restrict__ h1,
                                                unsigned short* __restrict__ hsb, int n) {
    int wid  = threadIdx.x >> 6;
    int lane = threadIdx.x & 63;
    int base = (blockIdx.x * 4 + wid) * 16;
    if (base >= n) return;
    int lrow = lane & 15;
    int kg   = lane >> 4;

    bf16x8 bfr[16];
#pragma unroll
    for (int t = 0; t < 16; ++t)
        bfr[t] = *(const bf16x8*)(Wt + lrow * NFEAT + t * 32 + kg * 8);

    int row = base + lrow;
    bool ok = (row < n);
    const float* xr = x + (size_t)(ok ? row : 0) * NFEAT;

    f32x4 acc = {0.f, 0.f, 0.f, 0.f};
#pragma unroll
    for (int t = 0; t < 16; ++t) {
        float4 u0 = *(const float4*)(xr + t * 32 + kg * 8);
        float4 u1 = *(const float4*)(xr + t * 32 + kg * 8 + 4);
        if (!ok) { u0 = make_float4(0,0,0,0); u1 = make_float4(0,0,0,0); }
        union { bf16x8 v; unsigned short u[8]; } A;
        A.u[0] = f2b_hw(u0.x); A.u[1] = f2b_hw(u0.y);
        A.u[2] = f2b_hw(u0.z); A.u[3] = f2b_hw(u0.w);
        A.u[4] = f2b_hw(u1.x); A.u[5] = f2b_hw(u1.y);
        A.u[6] = f2b_hw(u1.z); A.u[7] = f2b_hw(u1.w);
        acc = __builtin_amdgcn_mfma_f32_16x16x32_bf16(A.v, bfr[t], acc, 0, 0, 0);
    }

#pragma unroll
    for (int q = 0; q < 4; ++q) {
        int orow = base + kg * 4 + q;
        if (orow < n) {
            float v = acc[q];
            h1[(size_t)orow * HID + lrow] = v;
            hsb[(size_t)orow * HID + lrow] = f2b_hw(v * dis[orow]);
        }
    }
}

// ========== propagation: 64 sorted edges/wave, packed gather + carry merge ==
// r15 failed because its "chain-guarded" scan read BOTH shuffle operands from
// the pre-update val (4-run lost v3). Restored here: the r13/r14 PROVEN
// sequential-dependent 2-step suffix scan (second shfl_down reads UPDATED val),
// correct for sorted segments. Carry logic unchanged from r15 (case-walked).
__global__ __launch_bounds__(256) void prop_s64(const int2* __restrict__ pairs,
                                                const unsigned short* __restrict__ hsb,
                                                float* __restrict__ agg, int e) {
    int wave = blockIdx.x * 4 + (threadIdx.x >> 6);
    int lane = threadIdx.x & 63;
    long wbase = (long)wave * 64;
    if (wbase >= e) return;
    int slot = lane >> 4, j = lane & 15;
    int srcL0 = 4 * slot + (j >> 2);

    int dcar = -1; float vcar = 0.f;

#pragma unroll 1
    for (int w = 0; w < 4; ++w) {
        int ebase = (int)wbase + 16 * w;
        if (ebase >= e) break;
        int myE = ebase + (lane >> 2);
        int2 p = pairs[min(myE, e - 1)];
        uint2 g = *((const uint2*)(hsb + (size_t)p.x * HID) + (lane & 3));

#pragma unroll
        for (int r = 0; r < 4; ++r) {
            int sL = 16 * r + srcL0;
            int gx = __shfl((int)g.x, sL);
            int gy = __shfl((int)g.y, sL);
            int dd = __shfl(p.y, sL);
            int chosen = (j & 2) ? gy : gx;
            unsigned short hw = (j & 1) ? (unsigned short)(((unsigned)chosen) >> 16)
                                        : (unsigned short)(chosen & 0xffffu);
            int eidx = ebase + 4 * r + slot;
            bool valid = (eidx < e);
            int d = valid ? dd : -1;
            float val = valid ? b2f(hw) : 0.f;

            // PROVEN sequential-dependent suffix segmented scan (r13/r14):
            // second step reads the UPDATED val.
            int   dn1 = __shfl_down(d, 16);
            float vn1 = __shfl_down(val, 16);
            if (slot < 3 && dn1 == d) val += vn1;
            int   dn2 = __shfl_down(d, 32);
            float vn2 = __shfl_down(val, 32);
            if (slot < 2 && dn2 == d) val += vn2;

            // window scalars (uniform across the 4 slots for fixed j)
            int d0 = __shfl(d, j);
            int d1 = __shfl(d, 16 + j);
            int d2 = __shfl(d, 32 + j);
            int d3 = __shfl(d, 48 + j);
            // k = start slot of the run contiguous to slot 3
            int k = 3;
            if (d2 == d3) k = 2;
            if (k == 2 && d1 == d2) k = 1;
            if (k == 1 && d0 == d1) k = 0;
            float vlast = __shfl(val, 16 * k + j);

            int dp = __shfl_up(d, 16);
            bool leader = (d >= 0) && (slot == 0 || dp != d);

            // mid leaders flush, except the last-run leader (carried)
            if (leader && slot > 0 && !(slot == k && d3 >= 0))
                atomicAdd(&agg[(size_t)d * HID + j], val);

            // slot-0 lanes: carry management + first/last run
            if (slot == 0) {
                if (d0 >= 0 && d0 == dcar) {
                    if (k == 0) {                      // whole window = carry run
                        vcar += val;
                    } else {
                        atomicAdd(&agg[(size_t)dcar * HID + j], vcar + val);
                        if (d3 >= 0) { dcar = d3; vcar = vlast; }
                        else         { dcar = -1; vcar = 0.f; }
                    }
                } else {
                    if (dcar >= 0) atomicAdd(&agg[(size_t)dcar * HID + j], vcar);
                    dcar = -1; vcar = 0.f;
                    if (d0 >= 0) {
                        if (k == 0) {                  // single new run spans window
                            dcar = d0; vcar = val;
                        } else {
                            atomicAdd(&agg[(size_t)d0 * HID + j], val);
                            if (d3 >= 0) { dcar = d3; vcar = vlast; }
                        }
                    }
                }
            }
        }
    }
    if (slot == 0 && dcar >= 0)
        atomicAdd(&agg[(size_t)dcar * HID + j], vcar);
}

// ================= fused middle / final (proven) =================
__global__ __launch_bounds__(256) void mid(const float* __restrict__ agg1,
                                           float* __restrict__ h1,
                                           unsigned short* __restrict__ hsb,
                                           const float* __restrict__ dis,
                                           const float* __restrict__ b1,
                                           const float* __restrict__ W2, int n) {
    __shared__ float W2s[HID * HID];
    W2s[threadIdx.x] = W2[threadIdx.x];
    __syncthreads();
    int idx = blockIdx.x * 256 + threadIdx.x;
    int v = idx >> 4, j = idx & 15;
    if (v >= n) return;
    float dn = dis[v];
    float a = dn * agg1[idx] + dn * dn * h1[idx] + b1[j];
    float hv = fmaxf(a, 0.f);
    float h2 = 0.f;
#pragma unroll
    for (int k = 0; k < HID; ++k)
        h2 += __shfl(hv, k, HID) * W2s[k * HID + j];
    h1[idx] = h2;
    hsb[idx] = f2b_hw(h2 * dn);
}

__global__ __launch_bounds__(256) void finalk(float* __restrict__ out,
                                              const float* __restrict__ h2,
                                              const float* __restrict__ dis,
                                              const float* __restrict__ b2,
                                              const float* __restrict__ eps, int n) {
    int idx = blockIdx.x * 256 + threadIdx.x;
    int v = idx >> 4, j = idx & 15;
    if (v >= n) return;
    float dn = dis[v];
    float z = dn * out[idx] + dn * dn * h2[idx] + b2[j];
    out[idx] = z + eps[idx] * expf(0.5f * z);
}

// ================= fallback (round-7 atomic path) =================
__global__ __launch_bounds__(256) void deg_count_int(const int* __restrict__ dst,
                                                     int* __restrict__ ideg, int e) {
    int i = blockIdx.x * 256 + threadIdx.x;
    if (i < e) atomicAdd(&ideg[dst[i]], 1);
}
__global__ __launch_bounds__(256) void make_dis(const int* __restrict__ ideg,
                                                float* __restrict__ dis, int n) {
    int i = blockIdx.x * 256 + threadIdx.x;
    if (i < n) dis[i] = rsqrtf(1.0f + (float)ideg[i]);
}
__global__ __launch_bounds__(256) void prop(const int* __restrict__ src,
                                            const int* __restrict__ dst,
                                            const unsigned short* __restrict__ hsb,
                                            float* __restrict__ agg, int e) {
    int idx = blockIdx.x * 256 + threadIdx.x;
    int ed = idx >> 4, j = idx & 15;
    if (ed >= e) return;
    int s = src[ed], d = dst[ed];
    atomicAdd(&agg[(size_t)d * HID + j], b2f(hsb[(size_t)s * HID + j]));
}

static inline size_t al64(size_t x) { return (x + 63) & ~(size_t)63; }

extern "C" void kernel_launch(void* const* d_in, const int* in_sizes, int n_in,
                              void* d_out, int out_size, void* d_ws, size_t ws_size,
                              hipStream_t stream) {
    const float* x   = (const float*)d_in[0];
    const float* W1  = (const float*)d_in[1];
    const float* b1  = (const float*)d_in[2];
    const float* W2  = (const float*)d_in[3];
    const float* b2  = (const float*)d_in[4];
    const float* eps = (const float*)d_in[5];
    const int*   ei  = (const int*)d_in[6];

    int n = in_sizes[5] / HID;   // 100000
    int e = in_sizes[6] / 2;     // 3200000
    const int* srcs = ei;
    const int* dsts = ei + e;
    float* outf = (float*)d_out;

    int nbkt    = (n + BW - 1) / BW;         // 1563
    int nBlk    = (n + 255) / 256;
    int mmBlk   = (n + 63) / 64;
    int featBlk = (n * 16 + 255) / 256;
    int chBlk   = (e + CH - 1) / CH;         // 196

    // ws layout, 64B-aligned regions
    char* wp = (char*)d_ws;
    size_t o_pr   = 0;                                     // pairs int2
    size_t o_hsb  = al64(o_pr   + (size_t)e * 8);
    size_t o_h1   = al64(o_hsb  + (size_t)n * HID * 2);
    size_t o_agg1 = al64(o_h1   + (size_t)n * HID * 4);
    size_t o_dis  = al64(o_agg1 + (size_t)n * HID * 4);
    size_t o_gc   = al64(o_dis  + (size_t)n * 4);
    size_t o_go   = al64(o_gc   + (size_t)(MAXB + 2) * 4);
    size_t o_gu   = al64(o_go   + (size_t)(MAXB + 2) * 4);
    size_t o_wt   = al64(o_gu   + (size_t)(MAXB + 2) * 4);
    size_t need   = o_wt + 8192 * 2;
    bool sortedPath = (nbkt <= MAXB) && (ws_size >= need);

    if (sortedPath) {
        int2*           pairs   = (int2*)(wp + o_pr);
        unsigned short* hsb     = (unsigned short*)(wp + o_hsb);
        float*          h1      = (float*)(wp + o_h1);
        float*          agg1    = (float*)(wp + o_agg1);
        float*          dis     = (float*)(wp + o_dis);
        int*            gcount  = (int*)(wp + o_gc);
        int*            goff    = (int*)(wp + o_go);
        int*            gcursor = (int*)(wp + o_gu);
        unsigned short* Wt      = (unsigned short*)(wp + o_wt);

        size_t featBytes = (size_t)n * HID * sizeof(float);
        hipMemsetAsync(gcount, 0, (size_t)(MAXB + 2) * 4, stream);
        hipMemsetAsync(agg1, 0, featBytes, stream);
        hipMemsetAsync(outf, 0, featBytes, stream);

        khist<<<chBlk, 1024, 0, stream>>>(dsts, gcount, e, nbkt);
        kscan<<<1, 1024, 0, stream>>>(gcount, goff, gcursor, nbkt);
        kscatter<<<chBlk, 1024, 0, stream>>>(srcs, dsts, gcursor, pairs, e, nbkt);
        ksort<<<nbkt, 256, 0, stream>>>(pairs, goff, dis, n);

        prep_wt<<<32, 256, 0, stream>>>(W1, Wt);
        mm1_mfma<<<mmBlk, 256, 0, stream>>>(x, Wt, dis, h1, hsb, n);

        int waves = (e + 63) / 64;
        int psBlk = (waves + 3) / 4;
        prop_s64<<<psBlk, 256, 0, stream>>>(pairs, hsb, agg1, e);
        mid<<<featBlk, 256, 0, stream>>>(agg1, h1, hsb, dis, b1, W2, n);
        prop_s64<<<psBlk, 256, 0, stream>>>(pairs, hsb, outf, e);
        finalk<<<featBlk, 256, 0, stream>>>(outf, h1, dis, b2, eps, n);
    } else {
        // round-7 path (global fp32 atomics, 16 lanes/edge)
        char* fp = (char*)d_ws;
        size_t f_ideg = 0;
        size_t f_dis  = al64(f_ideg + (size_t)n * 4);
        size_t f_h1   = al64(f_dis  + (size_t)n * 4);
        size_t f_agg1 = al64(f_h1   + (size_t)n * HID * 4);
        size_t f_hsb  = al64(f_agg1 + (size_t)n * HID * 4);
        size_t f_wt   = al64(f_hsb  + (size_t)n * HID * 2);
        int*            ideg = (int*)(fp + f_ideg);
        float*          dis  = (float*)(fp + f_dis);
        float*          h1   = (float*)(fp + f_h1);
        float*          agg1 = (float*)(fp + f_agg1);
        unsigned short* hsb  = (unsigned short*)(fp + f_hsb);
        unsigned short* Wt   = (unsigned short*)(fp + f_wt);

        size_t featBytes = (size_t)n * HID * sizeof(float);
        hipMemsetAsync(ideg, 0, (size_t)n * sizeof(int), stream);
        hipMemsetAsync(agg1, 0, featBytes, stream);
        hipMemsetAsync(outf, 0, featBytes, stream);

        int eBlk    = (e + 255) / 256;
        int propBlk = (e * 16 + 255) / 256;
        prep_wt<<<32, 256, 0, stream>>>(W1, Wt);
        deg_count_int<<<eBlk, 256, 0, stream>>>(dsts, ideg, e);
        make_dis<<<nBlk, 256, 0, stream>>>(ideg, dis, n);
        mm1_mfma<<<mmBlk, 256, 0, stream>>>(x, Wt, dis, h1, hsb, n);
        prop<<<propBlk, 256, 0, stream>>>(srcs, dsts, hsb, agg1, e);
        mid<<<featBlk, 256, 0, stream>>>(agg1, h1, hsb, dis, b1, W2, n);
        prop<<<propBlk, 256, 0, stream>>>(srcs, dsts, hsb, outf, e);
        finalk<<<featBlk, 256, 0, stream>>>(outf, h1, dis, b2, eps, n);
    }
}

// Round 17
// 316.181 us; speedup vs baseline: 1.2823x; 1.2823x over previous
//
#include <hip/hip_runtime.h>
#include <hip/hip_bf16.h>

#define HID 16
#define NFEAT 512
#define BW 64           // nodes per bucket (dst >> 6)
#define CH 16384        // edges per histogram/scatter block
#define MAXB 2048       // max buckets supported by bucket path
#define SCAP 5120       // ksort LDS staging capacity (int2)

typedef __attribute__((ext_vector_type(8))) short bf16x8;
typedef __attribute__((ext_vector_type(4))) float f32x4;

__device__ __forceinline__ unsigned short f2b_hw(float f) {
    __hip_bfloat16 h = __float2bfloat16(f);
    return *reinterpret_cast<unsigned short*>(&h);
}
__device__ __forceinline__ float b2f(unsigned short b) {
    return __uint_as_float(((unsigned)b) << 16);
}

// ================= bucket build, fused histogram =================
// khist2 stores its per-block histogram to pbh (global, coalesced) so
// kscatter2 doesn't re-scan dst (saves 12.8MB read + 3.2M LDS atomics).
__global__ __launch_bounds__(1024) void khist2(const int* __restrict__ dst,
                                               int* __restrict__ gcount,
                                               int* __restrict__ pbh, int e, int nbkt) {
    __shared__ int hist[MAXB];
    for (int t = threadIdx.x; t < nbkt; t += 1024) hist[t] = 0;
    __syncthreads();
    int base = blockIdx.x * CH;
#pragma unroll
    for (int k = 0; k < CH / 1024; ++k) {
        int i = base + k * 1024 + threadIdx.x;
        if (i < e) atomicAdd(&hist[dst[i] >> 6], 1);
    }
    __syncthreads();
    int* row = pbh + (size_t)blockIdx.x * nbkt;
    for (int t = threadIdx.x; t < nbkt; t += 1024) {
        int h = hist[t];
        row[t] = h;
        if (h) atomicAdd(&gcount[t], h);
    }
}

__global__ __launch_bounds__(1024) void kscan(const int* __restrict__ gcount,
                                              int* __restrict__ goff,
                                              int* __restrict__ gcursor, int nbkt) {
    __shared__ int buf0[MAXB], buf1[MAXB];
    for (int t = threadIdx.x; t < MAXB; t += 1024) buf0[t] = (t < nbkt) ? gcount[t] : 0;
    __syncthreads();
    int* in = buf0; int* out = buf1;
    for (int d = 1; d < MAXB; d <<= 1) {
        for (int t = threadIdx.x; t < MAXB; t += 1024)
            out[t] = in[t] + (t >= d ? in[t - d] : 0);
        __syncthreads();
        int* tmp = in; in = out; out = tmp;
    }
    for (int t = threadIdx.x; t < nbkt; t += 1024) {
        int excl = in[t] - gcount[t];
        goff[t] = excl;
        gcursor[t] = excl;
    }
    if (threadIdx.x == 0) goff[nbkt] = in[nbkt - 1];
}

// scatter using precomputed per-block histogram (no re-scan, LDS halved)
__global__ __launch_bounds__(1024) void kscatter2(const int* __restrict__ src,
                                                  const int* __restrict__ dst,
                                                  int* __restrict__ gcursor,
                                                  const int* __restrict__ pbh,
                                                  int2* __restrict__ pairs, int e, int nbkt) {
    __shared__ int base[MAXB];
    const int* row = pbh + (size_t)blockIdx.x * nbkt;
    for (int t = threadIdx.x; t < nbkt; t += 1024) {
        int h = row[t];
        base[t] = h ? atomicAdd(&gcursor[t], h) : 0;
    }
    __syncthreads();
    int b0 = blockIdx.x * CH;
#pragma unroll
    for (int k = 0; k < CH / 1024; ++k) {
        int i = b0 + k * 1024 + threadIdx.x;
        if (i < e) {
            int d = dst[i];
            int pos = atomicAdd(&base[d >> 6], 1);   // LDS bump
            pairs[pos] = make_int2(src[i], d);
        }
    }
}

// ================= per-bucket counting sort by dst + dis (proven r13) =======
__global__ __launch_bounds__(256) void ksort(int2* __restrict__ pairs,
                                             const int* __restrict__ goff,
                                             float* __restrict__ dis, int n) {
    __shared__ int cnt[BW];
    __shared__ int ofs[BW];
    __shared__ int2 stg[SCAP];
    int b = blockIdx.x;
    int s0 = goff[b], s1 = goff[b + 1];
    int m = s1 - s0;
    if (threadIdx.x < BW) cnt[threadIdx.x] = 0;
    __syncthreads();
    bool fits = (m <= SCAP);
    if (fits) {
        for (int i = threadIdx.x; i < m; i += 256) {
            int2 p = pairs[s0 + i];
            stg[i] = p;
            atomicAdd(&cnt[p.y & (BW - 1)], 1);
        }
    } else {
        for (int i = threadIdx.x; i < m; i += 256)
            atomicAdd(&cnt[pairs[s0 + i].y & (BW - 1)], 1);
    }
    __syncthreads();
    if (threadIdx.x < BW) {
        int node = b * BW + threadIdx.x;
        if (node < n) dis[node] = rsqrtf(1.0f + (float)cnt[threadIdx.x]);
        int v = cnt[threadIdx.x];
        int inc = v;
        for (int d = 1; d < 64; d <<= 1) {
            int o = __shfl_up(inc, d);
            if (threadIdx.x >= (unsigned)d) inc += o;
        }
        ofs[threadIdx.x] = inc - v;
    }
    __syncthreads();
    if (fits) {
        for (int i = threadIdx.x; i < m; i += 256) {
            int2 p = stg[i];
            int pos = atomicAdd(&ofs[p.y & (BW - 1)], 1);
            pairs[s0 + pos] = p;
        }
    }
}

// ================= W1 -> Wt (bf16 transposed) =================
__global__ __launch_bounds__(256) void prep_wt(const float* __restrict__ W1,
                                               unsigned short* __restrict__ Wt) {
    int i = blockIdx.x * 256 + threadIdx.x;   // 8192 = 16*512
    int j = i >> 9, k = i & 511;
    Wt[i] = f2b_hw(W1[k * HID + j]);
}

// ================= h1 = x @ W1 via MFMA (proven round 7) =================
__global__ __launch_bounds__(256) void mm1_mfma(const float* __restrict__ x,
                                                const unsigned short* __restrict__ Wt,
                                                const float* __restrict__ dis,
                                                float* __restrict__ h1,
                                                unsigned short* __restrict__ hsb, int n) {
    int wid  = threadIdx.x >> 6;
    int lane = threadIdx.x & 63;
    int base = (blockIdx.x * 4 + wid) * 16;
    if (base >= n) return;
    int lrow = lane & 15;
    int kg   = lane >> 4;

    bf16x8 bfr[16];
#pragma unroll
    for (int t = 0; t < 16; ++t)
        bfr[t] = *(const bf16x8*)(Wt + lrow * NFEAT + t * 32 + kg * 8);

    int row = base + lrow;
    bool ok = (row < n);
    const float* xr = x + (size_t)(ok ? row : 0) * NFEAT;

    f32x4 acc = {0.f, 0.f, 0.f, 0.f};
#pragma unroll
    for (int t = 0; t < 16; ++t) {
        float4 u0 = *(const float4*)(xr + t * 32 + kg * 8);
        float4 u1 = *(const float4*)(xr + t * 32 + kg * 8 + 4);
        if (!ok) { u0 = make_float4(0,0,0,0); u1 = make_float4(0,0,0,0); }
        union { bf16x8 v; unsigned short u[8]; } A;
        A.u[0] = f2b_hw(u0.x); A.u[1] = f2b_hw(u0.y);
        A.u[2] = f2b_hw(u0.z); A.u[3] = f2b_hw(u0.w);
        A.u[4] = f2b_hw(u1.x); A.u[5] = f2b_hw(u1.y);
        A.u[6] = f2b_hw(u1.z); A.u[7] = f2b_hw(u1.w);
        acc = __builtin_amdgcn_mfma_f32_16x16x32_bf16(A.v, bfr[t], acc, 0, 0, 0);
    }

#pragma unroll
    for (int q = 0; q < 4; ++q) {
        int orow = base + kg * 4 + q;
        if (orow < n) {
            float v = acc[q];
            h1[(size_t)orow * HID + lrow] = v;
            hsb[(size_t)orow * HID + lrow] = f2b_hw(v * dis[orow]);
        }
    }
}

// ========= propagation: 16 edges/wave packed gather + run merge (PROVEN r14,
// 88us/pass). r16 showed deeper carry-merging trades 20us of RMW for 50us of
// VALU -> reverted to this exact form. =========
__global__ __launch_bounds__(256) void prop_s16(const int2* __restrict__ pairs,
                                                const unsigned short* __restrict__ hsb,
                                                float* __restrict__ agg, int e) {
    int wave = blockIdx.x * 4 + (threadIdx.x >> 6);
    int lane = threadIdx.x & 63;
    int ebase = wave * 16;
    if (ebase >= e) return;

    int myE = ebase + (lane >> 2);
    int2 p = pairs[min(myE, e - 1)];
    uint2 g = *((const uint2*)(hsb + (size_t)p.x * HID) + (lane & 3));

    int slot = lane >> 4, j = lane & 15;
    int srcL0 = 4 * slot + (j >> 2);

#pragma unroll
    for (int r = 0; r < 4; ++r) {
        int sL = 16 * r + srcL0;
        int gx = __shfl((int)g.x, sL);
        int gy = __shfl((int)g.y, sL);
        int dd = __shfl(p.y, sL);
        int chosen = (j & 2) ? gy : gx;
        unsigned short hw = (j & 1) ? (unsigned short)(((unsigned)chosen) >> 16)
                                    : (unsigned short)(chosen & 0xffffu);
        int eidx = ebase + 4 * r + slot;
        bool valid = (eidx < e);
        int d = valid ? dd : -1;
        float val = valid ? b2f(hw) : 0.f;

        int   dn1 = __shfl_down(d, 16);
        float vn1 = __shfl_down(val, 16);
        if (slot < 3 && dn1 == d) val += vn1;
        int   dn2 = __shfl_down(d, 32);
        float vn2 = __shfl_down(val, 32);
        if (slot < 2 && dn2 == d) val += vn2;
        int dp = __shfl_up(d, 16);
        bool leader = (d >= 0) && (slot == 0 || dp != d);
        if (leader) atomicAdd(&agg[(size_t)d * HID + j], val);
    }
}

// ================= fused middle / final (proven) =================
__global__ __launch_bounds__(256) void mid(const float* __restrict__ agg1,
                                           float* __restrict__ h1,
                                           unsigned short* __restrict__ hsb,
                                           const float* __restrict__ dis,
                                           const float* __restrict__ b1,
                                           const float* __restrict__ W2, int n) {
    __shared__ float W2s[HID * HID];
    W2s[threadIdx.x] = W2[threadIdx.x];
    __syncthreads();
    int idx = blockIdx.x * 256 + threadIdx.x;
    int v = idx >> 4, j = idx & 15;
    if (v >= n) return;
    float dn = dis[v];
    float a = dn * agg1[idx] + dn * dn * h1[idx] + b1[j];
    float hv = fmaxf(a, 0.f);
    float h2 = 0.f;
#pragma unroll
    for (int k = 0; k < HID; ++k)
        h2 += __shfl(hv, k, HID) * W2s[k * HID + j];
    h1[idx] = h2;
    hsb[idx] = f2b_hw(h2 * dn);
}

__global__ __launch_bounds__(256) void finalk(float* __restrict__ out,
                                              const float* __restrict__ h2,
                                              const float* __restrict__ dis,
                                              const float* __restrict__ b2,
                                              const float* __restrict__ eps, int n) {
    int idx = blockIdx.x * 256 + threadIdx.x;
    int v = idx >> 4, j = idx & 15;
    if (v >= n) return;
    float dn = dis[v];
    float z = dn * out[idx] + dn * dn * h2[idx] + b2[j];
    out[idx] = z + eps[idx] * expf(0.5f * z);
}

// ================= fallback (round-7 atomic path) =================
__global__ __launch_bounds__(256) void deg_count_int(const int* __restrict__ dst,
                                                     int* __restrict__ ideg, int e) {
    int i = blockIdx.x * 256 + threadIdx.x;
    if (i < e) atomicAdd(&ideg[dst[i]], 1);
}
__global__ __launch_bounds__(256) void make_dis(const int* __restrict__ ideg,
                                                float* __restrict__ dis, int n) {
    int i = blockIdx.x * 256 + threadIdx.x;
    if (i < n) dis[i] = rsqrtf(1.0f + (float)ideg[i]);
}
__global__ __launch_bounds__(256) void prop(const int* __restrict__ src,
                                            const int* __restrict__ dst,
                                            const unsigned short* __restrict__ hsb,
                                            float* __restrict__ agg, int e) {
    int idx = blockIdx.x * 256 + threadIdx.x;
    int ed = idx >> 4, j = idx & 15;
    if (ed >= e) return;
    int s = src[ed], d = dst[ed];
    atomicAdd(&agg[(size_t)d * HID + j], b2f(hsb[(size_t)s * HID + j]));
}

static inline size_t al64(size_t x) { return (x + 63) & ~(size_t)63; }

extern "C" void kernel_launch(void* const* d_in, const int* in_sizes, int n_in,
                              void* d_out, int out_size, void* d_ws, size_t ws_size,
                              hipStream_t stream) {
    const float* x   = (const float*)d_in[0];
    const float* W1  = (const float*)d_in[1];
    const float* b1  = (const float*)d_in[2];
    const float* W2  = (const float*)d_in[3];
    const float* b2  = (const float*)d_in[4];
    const float* eps = (const float*)d_in[5];
    const int*   ei  = (const int*)d_in[6];

    int n = in_sizes[5] / HID;   // 100000
    int e = in_sizes[6] / 2;     // 3200000
    const int* srcs = ei;
    const int* dsts = ei + e;
    float* outf = (float*)d_out;

    int nbkt    = (n + BW - 1) / BW;         // 1563
    int nBlk    = (n + 255) / 256;
    int mmBlk   = (n + 63) / 64;
    int featBlk = (n * 16 + 255) / 256;
    int chBlk   = (e + CH - 1) / CH;         // 196

    // ws layout, 64B-aligned regions (identical footprint to r14)
    char* wp = (char*)d_ws;
    size_t o_pr   = 0;                                     // pairs int2
    size_t o_hsb  = al64(o_pr   + (size_t)e * 8);
    size_t o_h1   = al64(o_hsb  + (size_t)n * HID * 2);
    size_t o_agg1 = al64(o_h1   + (size_t)n * HID * 4);
    size_t o_dis  = al64(o_agg1 + (size_t)n * HID * 4);
    size_t o_gc   = al64(o_dis  + (size_t)n * 4);
    size_t o_go   = al64(o_gc   + (size_t)(MAXB + 2) * 4);
    size_t o_gu   = al64(o_go   + (size_t)(MAXB + 2) * 4);
    size_t o_wt   = al64(o_gu   + (size_t)(MAXB + 2) * 4);
    size_t need   = o_wt + 8192 * 2;
    // pbh (per-block hist) aliases agg1, which is dead until after kscatter2
    bool pbhFits  = (size_t)chBlk * nbkt * 4 <= (size_t)n * HID * 4;
    bool sortedPath = (nbkt <= MAXB) && pbhFits && (ws_size >= need);

    if (sortedPath) {
        int2*           pairs   = (int2*)(wp + o_pr);
        unsigned short* hsb     = (unsigned short*)(wp + o_hsb);
        float*          h1      = (float*)(wp + o_h1);
        float*          agg1    = (float*)(wp + o_agg1);
        float*          dis     = (float*)(wp + o_dis);
        int*            gcount  = (int*)(wp + o_gc);
        int*            goff    = (int*)(wp + o_go);
        int*            gcursor = (int*)(wp + o_gu);
        unsigned short* Wt      = (unsigned short*)(wp + o_wt);
        int*            pbh     = (int*)agg1;              // aliased, dead region

        size_t featBytes = (size_t)n * HID * sizeof(float);
        hipMemsetAsync(gcount, 0, (size_t)(MAXB + 2) * 4, stream);

        khist2<<<chBlk, 1024, 0, stream>>>(dsts, gcount, pbh, e, nbkt);
        kscan<<<1, 1024, 0, stream>>>(gcount, goff, gcursor, nbkt);
        kscatter2<<<chBlk, 1024, 0, stream>>>(srcs, dsts, gcursor, pbh, pairs, e, nbkt);
        // pbh dead from here; now zero agg1 / out accumulators
        hipMemsetAsync(agg1, 0, featBytes, stream);
        hipMemsetAsync(outf, 0, featBytes, stream);
        ksort<<<nbkt, 256, 0, stream>>>(pairs, goff, dis, n);

        prep_wt<<<32, 256, 0, stream>>>(W1, Wt);
        mm1_mfma<<<mmBlk, 256, 0, stream>>>(x, Wt, dis, h1, hsb, n);

        int waves = (e + 15) / 16;
        int psBlk = (waves + 3) / 4;
        prop_s16<<<psBlk, 256, 0, stream>>>(pairs, hsb, agg1, e);
        mid<<<featBlk, 256, 0, stream>>>(agg1, h1, hsb, dis, b1, W2, n);
        prop_s16<<<psBlk, 256, 0, stream>>>(pairs, hsb, outf, e);
        finalk<<<featBlk, 256, 0, stream>>>(outf, h1, dis, b2, eps, n);
    } else {
        // round-7 path (global fp32 atomics, 16 lanes/edge)
        char* fp = (char*)d_ws;
        size_t f_ideg = 0;
        size_t f_dis  = al64(f_ideg + (size_t)n * 4);
        size_t f_h1   = al64(f_dis  + (size_t)n * 4);
        size_t f_agg1 = al64(f_h1   + (size_t)n * HID * 4);
        size_t f_hsb  = al64(f_agg1 + (size_t)n * HID * 4);
        size_t f_wt   = al64(f_hsb  + (size_t)n * HID * 2);
        int*            ideg = (int*)(fp + f_ideg);
        float*          dis  = (float*)(fp + f_dis);
        float*          h1   = (float*)(fp + f_h1);
        float*          agg1 = (float*)(fp + f_agg1);
        unsigned short* hsb  = (unsigned short*)(fp + f_hsb);
        unsigned short* Wt   = (unsigned short*)(fp + f_wt);

        size_t featBytes = (size_t)n * HID * sizeof(float);
        hipMemsetAsync(ideg, 0, (size_t)n * sizeof(int), stream);
        hipMemsetAsync(agg1, 0, featBytes, stream);
        hipMemsetAsync(outf, 0, featBytes, stream);

        int eBlk    = (e + 255) / 256;
        int propBlk = (e * 16 + 255) / 256;
        prep_wt<<<32, 256, 0, stream>>>(W1, Wt);
        deg_count_int<<<eBlk, 256, 0, stream>>>(dsts, ideg, e);
        make_dis<<<nBlk, 256, 0, stream>>>(ideg, dis, n);
        mm1_mfma<<<mmBlk, 256, 0, stream>>>(x, Wt, dis, h1, hsb, n);
        prop<<<propBlk, 256, 0, stream>>>(srcs, dsts, hsb, agg1, e);
        mid<<<featBlk, 256, 0, stream>>>(agg1, h1, hsb, dis, b1, W2, n);
        prop<<<propBlk, 256, 0, stream>>>(srcs, dsts, hsb, outf, e);
        finalk<<<featBlk, 256, 0, stream>>>(outf, h1, dis, b2, eps, n);
    }
}